// Round 10
// baseline (344.659 us; speedup 1.0000x reference)
//
#include <hip/hip_runtime.h>
#include <cstdint>
#include <cstddef>

// ---------------------------------------------------------------------------
// Fused GQA MHA: B=2 S=2048 D=2048, G=4 HPG=4 DH=128 (16 heads)
// fused fp32->bf16 | gemm256 (Q proj) + gemm_kv (K, V^T) | flash attn | O proj
// ---------------------------------------------------------------------------

typedef __attribute__((ext_vector_type(8)))  __bf16 bf16x8;
typedef __attribute__((ext_vector_type(4)))  __bf16 bf16x4;
typedef __attribute__((ext_vector_type(4)))  float  f32x4;
typedef __attribute__((ext_vector_type(16))) float  f32x16;
typedef __attribute__((ext_vector_type(4)))  unsigned int u32x4;

#define GLD16(gp, lp) __builtin_amdgcn_global_load_lds(                         \
    (__attribute__((address_space(1))) void*)(size_t)(gp),                     \
    (__attribute__((address_space(3))) void*)(lp), 16, 0, 0)

#define PLSWAP(a, b) asm volatile("v_permlane32_swap_b32 %0, %1" : "+v"(a), "+v"(b))
#define EXP2F(x) __builtin_amdgcn_exp2f(x)

static __device__ __forceinline__ unsigned pack2bf(float a, float b) {
    unsigned short ua = __builtin_bit_cast(unsigned short, (__bf16)a);
    unsigned short ub = __builtin_bit_cast(unsigned short, (__bf16)b);
    return (unsigned)ua | ((unsigned)ub << 16);
}

// ---------------------------------------------------------------------------
// Fused fp32->bf16 for all 7 tensors in one launch
// ---------------------------------------------------------------------------
struct F2BArgs {
    const float* src[7];
    __bf16* dst[7];
    long beg[8];
};
__global__ void f2b_multi(F2BArgs a) {
    const long total = a.beg[7];
    const long stride = (long)gridDim.x * blockDim.x;
    for (long i = (long)blockIdx.x * blockDim.x + threadIdx.x; i < total; i += stride) {
        int s = 0;
#pragma unroll
        for (int j = 1; j < 7; ++j) s += (i >= a.beg[j]);
        long off = i - a.beg[s];
        const float4* p = (const float4*)(a.src[s] + off * 8);
        float4 x = p[0], y = p[1];
        bf16x8 r;
        r[0] = (__bf16)x.x; r[1] = (__bf16)x.y; r[2] = (__bf16)x.z; r[3] = (__bf16)x.w;
        r[4] = (__bf16)y.x; r[5] = (__bf16)y.y; r[6] = (__bf16)y.z; r[7] = (__bf16)y.w;
        *(bf16x8*)(a.dst[s] + off * 8) = r;
    }
}

// ---------------------------------------------------------------------------
// gemm256: BM=256 BN=128 BK=64, 8 waves, triple-buffered, counted vmcnt(6)
// (unchanged — verified R6)
// ---------------------------------------------------------------------------
template <int OUTF32>
__global__ __launch_bounds__(512)
void gemm256(const __bf16* __restrict__ A, const __bf16* __restrict__ Bm,
             const float* __restrict__ bias, float* __restrict__ Cf,
             __bf16* __restrict__ Cb, int M, int N, int K, int nbx) {
    __shared__ __bf16 As[3][256 * 64];
    __shared__ __bf16 Bs[3][128 * 64];
    const int tid = threadIdx.x, lane = tid & 63, wid = tid >> 6;
    const int g = lane >> 4, c = lane & 15;
    const int wr = wid >> 1, wc = wid & 1;
    const int cpx = gridDim.x >> 3;
    const int swz = ((int)blockIdx.x & 7) * cpx + ((int)blockIdx.x >> 3);
    const int bx = swz % nbx, by = swz / nbx;
    const int m0 = by * 256, n0 = bx * 128;
    const int nkt = K >> 6;

    const f32x4 z = {0.f, 0.f, 0.f, 0.f};
    f32x4 acc[4][4];
#pragma unroll
    for (int i = 0; i < 4; ++i)
#pragma unroll
        for (int j = 0; j < 4; ++j) acc[i][j] = z;

    auto stageA = [&](int b, int kt, int h) {
        if (kt >= nkt) return;
        const __bf16* src = A + (size_t)m0 * K + (size_t)kt * 64;
#pragma unroll
        for (int i = 0; i < 2; ++i) {
            int ci = h * 1024 + i * 512 + tid;
            int row = ci >> 3, chg = (ci & 7) ^ (row & 7);
            GLD16(src + (size_t)row * K + chg * 8, &As[b][ci * 8]);
        }
    };
    auto stageB = [&](int b, int kt) {
        if (kt >= nkt) return;
        const __bf16* src = Bm + (size_t)n0 * K + (size_t)kt * 64;
#pragma unroll
        for (int i = 0; i < 2; ++i) {
            int ci = i * 512 + tid;
            int row = ci >> 3, chg = (ci & 7) ^ (row & 7);
            GLD16(src + (size_t)row * K + chg * 8, &Bs[b][ci * 8]);
        }
    };

    stageA(0, 0, 0); stageA(0, 0, 1); stageB(0, 0);
    stageA(1, 1, 0); stageA(1, 1, 1); stageB(1, 1);
    asm volatile("s_waitcnt vmcnt(6)" ::: "memory");
    __builtin_amdgcn_sched_barrier(0);
    __builtin_amdgcn_s_barrier();

    int bd = 0;
    for (int kt = 0; kt < nkt; ++kt) {
        const int bs = (bd >= 1) ? bd - 1 : 2;
        bf16x8 af[4], bfr[4];
#pragma unroll
        for (int ph = 0; ph < 2; ++ph) {
#pragma unroll
            for (int mi = 0; mi < 4; ++mi) {
                int row = wr * 64 + mi * 16 + c;
                int ch = (ph * 4 + g) ^ (c & 7);
                af[mi] = *(const bf16x8*)&As[bd][row * 64 + ch * 8];
            }
#pragma unroll
            for (int ni = 0; ni < 4; ++ni) {
                int row = wc * 64 + ni * 16 + c;
                int ch = (ph * 4 + g) ^ (c & 7);
                bfr[ni] = *(const bf16x8*)&Bs[bd][row * 64 + ch * 8];
            }
            if (ph == 0) {
                stageA(bs, kt + 2, 0);
            } else {
                stageA(bs, kt + 2, 1);
                stageB(bs, kt + 2);
            }
            __builtin_amdgcn_s_barrier();
            asm volatile("s_waitcnt lgkmcnt(0)" ::: "memory");
            __builtin_amdgcn_sched_barrier(0);
            __builtin_amdgcn_s_setprio(1);
#pragma unroll
            for (int mi = 0; mi < 4; ++mi)
#pragma unroll
                for (int ni = 0; ni < 4; ++ni)
                    acc[mi][ni] = __builtin_amdgcn_mfma_f32_16x16x32_bf16(
                        af[mi], bfr[ni], acc[mi][ni], 0, 0, 0);
            __builtin_amdgcn_s_setprio(0);
            if (ph == 1) {
                if (kt >= nkt - 2) asm volatile("s_waitcnt vmcnt(0)" ::: "memory");
                else               asm volatile("s_waitcnt vmcnt(6)" ::: "memory");
                __builtin_amdgcn_sched_barrier(0);
            }
            __builtin_amdgcn_s_barrier();
        }
        bd = (bd >= 2) ? 0 : bd + 1;
    }

#pragma unroll
    for (int mi = 0; mi < 4; ++mi) {
#pragma unroll
        for (int ni = 0; ni < 4; ++ni) {
            int col = n0 + wc * 64 + ni * 16 + c;
            float bvc = bias[col];
#pragma unroll
            for (int r = 0; r < 4; ++r) {
                int row = m0 + wr * 64 + mi * 16 + g * 4 + r;
                float v = acc[mi][ni][r] + bvc;
                if (OUTF32) Cf[(size_t)row * N + col] = v;
                else        Cb[(size_t)row * N + col] = (__bf16)v;
            }
        }
    }
}

// ---------------------------------------------------------------------------
// m97-structure tile body for the small K/V projections (unchanged)
// ---------------------------------------------------------------------------
static __device__ __forceinline__
void gemm_tile(const __bf16* __restrict__ A, const __bf16* __restrict__ Bm,
               const float* __restrict__ bias,
               __bf16* __restrict__ Cb, int N, int K, int m0, int n0, int biasrow,
               __bf16* As, __bf16* Bs) {
    const int tid = threadIdx.x;
    const int lane = tid & 63, wid = tid >> 6;
    const int g = lane >> 4, c = lane & 15;
    const int wr = wid >> 1, wc = wid & 1;

    const f32x4 z = {0.f, 0.f, 0.f, 0.f};
    f32x4 acc[4][4];
#pragma unroll
    for (int i = 0; i < 4; ++i)
#pragma unroll
        for (int j = 0; j < 4; ++j) acc[i][j] = z;

    const int nk = K >> 5;
#pragma unroll
    for (int i = 0; i < 2; ++i) {
        int ci = i * 256 + tid, row = ci >> 2, kc = (ci & 3) * 8;
        GLD16(A + (size_t)(m0 + row) * K + kc, As + ci * 8);
        GLD16(Bm + (size_t)(n0 + row) * K + kc, Bs + ci * 8);
    }
    __syncthreads();

    int cur = 0;
    for (int t = 0; t < nk; ++t) {
        if (t + 1 < nk) {
            int koff = (t + 1) * 32;
            int nb = (cur ^ 1) * 4096;
#pragma unroll
            for (int i = 0; i < 2; ++i) {
                int ci = i * 256 + tid, row = ci >> 2, kc = (ci & 3) * 8;
                GLD16(A + (size_t)(m0 + row) * K + koff + kc, As + nb + ci * 8);
                GLD16(Bm + (size_t)(n0 + row) * K + koff + kc, Bs + nb + ci * 8);
            }
        }
        int cb = cur * 4096;
        bf16x8 af[4], bfv[4];
#pragma unroll
        for (int im = 0; im < 4; ++im)
            af[im] = *(const bf16x8*)&As[cb + (wr * 64 + im * 16 + c) * 32 + g * 8];
#pragma unroll
        for (int in = 0; in < 4; ++in)
            bfv[in] = *(const bf16x8*)&Bs[cb + (wc * 64 + in * 16 + c) * 32 + g * 8];
        __builtin_amdgcn_s_setprio(1);
#pragma unroll
        for (int im = 0; im < 4; ++im)
#pragma unroll
            for (int in = 0; in < 4; ++in)
                acc[im][in] = __builtin_amdgcn_mfma_f32_16x16x32_bf16(
                    af[im], bfv[in], acc[im][in], 0, 0, 0);
        __builtin_amdgcn_s_setprio(0);
        __syncthreads();
        cur ^= 1;
    }

#pragma unroll
    for (int im = 0; im < 4; ++im) {
#pragma unroll
        for (int in = 0; in < 4; ++in) {
            int col = n0 + wc * 64 + in * 16 + c;
            float bvc = biasrow ? 0.f : bias[col];
#pragma unroll
            for (int r = 0; r < 4; ++r) {
                int row = m0 + wr * 64 + im * 16 + g * 4 + r;
                float v = acc[im][in][r] + (biasrow ? bias[row] : bvc);
                Cb[(size_t)row * N + col] = (__bf16)v;
            }
        }
    }
}

__global__ __launch_bounds__(256)
void gemm_kv(const __bf16* __restrict__ kb, const __bf16* __restrict__ wkb,
             const float* __restrict__ bK, __bf16* __restrict__ kp,
             const __bf16* __restrict__ wvb, const __bf16* __restrict__ vb,
             const float* __restrict__ bV, __bf16* __restrict__ vpT) {
    __shared__ __bf16 As[2 * 128 * 32];
    __shared__ __bf16 Bs[2 * 128 * 32];
    const int bid = blockIdx.x;
    const int swz = (bid & 7) * 32 + (bid >> 3);
    if (swz < 128) {
        int bx = swz & 31, by = swz >> 5;
        gemm_tile(kb, wkb, bK, kp, 512, 2048, bx * 128, by * 128, 0, As, Bs);
    } else {
        int s2 = swz - 128;
        int bx = s2 & 3, by = s2 >> 2;
        gemm_tile(wvb, vb, bV, vpT, 4096, 2048, bx * 128, by * 128, 1, As, Bs);
    }
}

// ---------------------------------------------------------------------------
// Flash attention: split-K across wave groups (16 waves/CU).
// Block = 512 thr = 8 waves; waves 0-3 (grp g=0) do keys [0,1024),
// waves 4-7 (g=1) keys [1024,2048), same 128 q-rows. Per iter one joint
// 64-key stage (rows 0-31 = g0 tile, 32-63 = g1 tile), R5-verified swizzles.
// End: split-K merge via LDS (o,m,l exchange, reusing retired K/V region).
// ---------------------------------------------------------------------------
__global__ __launch_bounds__(512, 4)
void attn_kernel(const __bf16* __restrict__ Qw, const __bf16* __restrict__ Kw,
                 const __bf16* __restrict__ VTw, __bf16* __restrict__ Ow) {
    constexpr int S = 2048, DQ = 2048, DKV = 512, TOK = 4096;
    constexpr int nt = 32;                       // 32 tiles of 32 keys per group
    const int bid = blockIdx.x;
    const int xcd = bid & 7, slot = bid >> 3;    // grid 512: slot in [0,64)
    const int b = xcd >> 2, grp = xcd & 3;
    const int head = grp * 4 + (slot & 3);
    const int qblk = slot >> 2;                  // [0,16)
    const int t0 = slot & (nt - 1);              // stagger start tile
    const __bf16* Q   = Qw + (size_t)b * S * DQ + head * 128;
    const __bf16* Kp  = Kw + (size_t)b * S * DKV + grp * 128;
    const __bf16* VTp = VTw + (size_t)(grp * 128) * TOK + (size_t)b * S;
    __bf16* Op = Ow + (size_t)b * S * DQ + head * 128;

    // 64 KB shared region: K[2][64*128] + V^T[2][128*64] during the loop;
    // reused as the split-K o-exchange buffer afterwards.
    __shared__ __align__(16) char smem[65536];
    __shared__ float mlx[4][64][2];
    __bf16* Ks = (__bf16*)smem;                  // [2][64*128]
    __bf16* Vs = (__bf16*)(smem + 32768);        // [2][128*64]

    const int tid = threadIdx.x, wid = tid >> 6, lane = tid & 63;
    const int ql = lane & 31, hi = lane >> 5;
    const int g = wid >> 2;                      // key-split group
    const int qrow = qblk * 128 + (wid & 3) * 32 + ql;
    const int kbase = g * 1024;                  // group's global key offset

    bf16x8 qf[8];
#pragma unroll
    for (int ks = 0; ks < 8; ++ks)
        qf[ks] = *(const bf16x8*)(Q + (size_t)qrow * DQ + ks * 16 + hi * 8);

    f32x16 o[4];
#pragma unroll
    for (int d = 0; d < 4; ++d)
#pragma unroll
        for (int r = 0; r < 16; ++r) o[d][r] = 0.f;
    float mprev = -1e30f, lsum = 0.f;
    constexpr float kexp = 0.08838834764831845f * 1.4426950408889634f;
    constexpr float THR = 8.0f / kexp;

    // joint stage: K rows 0-31 <- g0 keys, 32-63 <- g1 keys (R5 swizzle);
    // V^T rows [128], key-chunks 0-3 <- g0, 4-7 <- g1, s(dh)=(dh^(dh>>3))&7
    auto stage = [&](int buf, int t) {
        int ta = (t0 + t) & (nt - 1);
#pragma unroll
        for (int i = 0; i < 2; ++i) {            // K: 1024 chunks
            int ci = i * 512 + tid;
            int key = ci >> 4, ccl = ci & 15, ccg = ccl ^ (key & 15);
            int gk = (key & 31) + ta * 32 + ((key >> 5) << 10);
            GLD16(Kp + (size_t)gk * DKV + ccg * 8, &Ks[buf * 8192 + ci * 8]);
        }
#pragma unroll
        for (int i = 0; i < 2; ++i) {            // V^T: 1024 chunks
            int ci = i * 512 + tid;
            int dh = ci >> 3, cl = ci & 7;
            int cg = cl ^ ((dh ^ (dh >> 3)) & 7);
            int gko = ((cg >> 2) << 10) + ta * 32 + (cg & 3) * 8;
            GLD16(VTp + (size_t)dh * TOK + gko, &Vs[buf * 8192 + ci * 8]);
        }
    };

    stage(0, 0);
    asm volatile("s_waitcnt vmcnt(0)" ::: "memory");
    asm volatile("s_barrier" ::: "memory");

    int cur = 0;
    for (int i = 0; i < nt; ++i) {
        if (i + 1 < nt) stage(cur ^ 1, i + 1);   // issue early; lands by bottom

        // ---- QK^T: sc = K(32x128) x Q^T(128x32); rows g*32..g*32+31
        f32x16 sc;
#pragma unroll
        for (int r = 0; r < 16; ++r) sc[r] = 0.f;
        __builtin_amdgcn_s_setprio(1);
#pragma unroll
        for (int ks = 0; ks < 8; ++ks) {
            int key_l = g * 32 + ql;
            int chl = (ks * 2 + hi) ^ (ql & 15);
            bf16x8 kf = *(const bf16x8*)&Ks[cur * 8192 + key_l * 128 + chl * 8];
            sc = __builtin_amdgcn_mfma_f32_32x32x16_bf16(kf, qf[ks], sc, 0, 0, 0);
        }
        __builtin_amdgcn_s_setprio(0);

        // ---- online softmax (lane-local q = ql)
        float mo = sc[0];
#pragma unroll
        for (int r = 1; r < 16; ++r) mo = fmaxf(mo, sc[r]);
        mo = fmaxf(mo, __shfl_xor(mo, 32, 64));
        if (!__all(mo - mprev <= THR)) {         // T13 defer-max
            float mn = fmaxf(mprev, mo);
            float ef = EXP2F((mprev - mn) * kexp);
            lsum *= ef;
#pragma unroll
            for (int d = 0; d < 4; ++d)
#pragma unroll
                for (int r = 0; r < 16; ++r) o[d][r] *= ef;
            mprev = mn;
        }
        float mnk = mprev * kexp;
        float rs = 0.f;
#pragma unroll
        for (int r = 0; r < 16; ++r) {
            float p = EXP2F(__builtin_fmaf(sc[r], kexp, -mnk));
            sc[r] = p;
            rs += p;
        }
        rs += __shfl_xor(rs, 32, 64);
        lsum += rs;

        // ---- pack P: pk[rg] covers keys {0..3}+8rg+4hi (group-local)
        unsigned pk[4][2];
#pragma unroll
        for (int rg = 0; rg < 4; ++rg) {
            pk[rg][0] = pack2bf(sc[rg * 4 + 0], sc[rg * 4 + 1]);
            pk[rg][1] = pack2bf(sc[rg * 4 + 2], sc[rg * 4 + 3]);
        }

        // ---- PV: o[dht] += V^T(32x16) x P(16x32); key-chunks g*4+e*2+hi
        __builtin_amdgcn_s_setprio(1);
#pragma unroll
        for (int e = 0; e < 2; ++e) {
            unsigned a0 = pk[2 * e][0], b0 = pk[2 * e + 1][0];
            unsigned a1 = pk[2 * e][1], b1 = pk[2 * e + 1][1];
            PLSWAP(a0, b0);
            PLSWAP(a1, b1);
            u32x4 fw = {a0, a1, b0, b1};
            bf16x8 pf = __builtin_bit_cast(bf16x8, fw);
#pragma unroll
            for (int dht = 0; dht < 4; ++dht) {
                int dh = dht * 32 + ql;
                int chl = (g * 4 + e * 2 + hi) ^ ((dh ^ (dh >> 3)) & 7);
                bf16x8 vf = *(const bf16x8*)&Vs[cur * 8192 + dh * 64 + chl * 8];
                o[dht] = __builtin_amdgcn_mfma_f32_32x32x16_bf16(vf, pf, o[dht], 0, 0, 0);
            }
        }
        __builtin_amdgcn_s_setprio(0);

        asm volatile("s_waitcnt vmcnt(0)" ::: "memory");   // t+1 landed
        asm volatile("s_barrier" ::: "memory");
        cur ^= 1;
    }

    // ---- split-K merge: waves 4-7 publish (o,m,l); waves 0-3 combine+store.
    float4* ox = (float4*)smem;                  // [4 waves][16 chunks][64 lanes]
    if (g == 1) {
        int w4 = wid & 3;
#pragma unroll
        for (int dht = 0; dht < 4; ++dht)
#pragma unroll
            for (int rg = 0; rg < 4; ++rg) {
                float4 v = {o[dht][rg * 4 + 0], o[dht][rg * 4 + 1],
                            o[dht][rg * 4 + 2], o[dht][rg * 4 + 3]};
                ox[((w4 * 16 + dht * 4 + rg) << 6) + lane] = v;
            }
        mlx[w4][lane][0] = mprev;
        mlx[w4][lane][1] = lsum;
    }
    __syncthreads();
    if (g == 0) {
        float m2 = mlx[wid][lane][0], l2 = mlx[wid][lane][1];
        float mF = fmaxf(mprev, m2);
        float e1 = EXP2F((mprev - mF) * kexp);
        float e2 = EXP2F((m2 - mF) * kexp);
        float linv = 1.0f / (lsum * e1 + l2 * e2);
#pragma unroll
        for (int dht = 0; dht < 4; ++dht)
#pragma unroll
            for (int rg = 0; rg < 4; ++rg) {
                float4 p = ox[((wid * 16 + dht * 4 + rg) << 6) + lane];
                bf16x4 wv;
                wv[0] = (__bf16)((o[dht][rg * 4 + 0] * e1 + p.x * e2) * linv);
                wv[1] = (__bf16)((o[dht][rg * 4 + 1] * e1 + p.y * e2) * linv);
                wv[2] = (__bf16)((o[dht][rg * 4 + 2] * e1 + p.z * e2) * linv);
                wv[3] = (__bf16)((o[dht][rg * 4 + 3] * e1 + p.w * e2) * linv);
                int dh0 = dht * 32 + rg * 8 + hi * 4;
                *(bf16x4*)(Op + (size_t)qrow * DQ + dh0) = wv;
            }
    }
}

// ---------------------------------------------------------------------------
extern "C" void kernel_launch(void* const* d_in, const int* in_sizes, int n_in,
                              void* d_out, int out_size, void* d_ws, size_t ws_size,
                              hipStream_t stream) {
    (void)in_sizes; (void)n_in; (void)out_size; (void)ws_size;
    const float* query = (const float*)d_in[0];
    const float* key   = (const float*)d_in[1];
    const float* value = (const float*)d_in[2];
    const float* WQ = (const float*)d_in[3];
    const float* bQ = (const float*)d_in[4];
    const float* WK = (const float*)d_in[5];
    const float* bK = (const float*)d_in[6];
    const float* WV = (const float*)d_in[7];
    const float* bV = (const float*)d_in[8];
    const float* WO = (const float*)d_in[9];
    const float* bO = (const float*)d_in[10];
    float* out = (float*)d_out;

    __bf16* w = (__bf16*)d_ws;
    __bf16* qb  = w; w += (size_t)4096 * 2048;
    __bf16* kb  = w; w += (size_t)4096 * 2048;
    __bf16* vb  = w; w += (size_t)4096 * 2048;
    __bf16* wqb = w; w += (size_t)2048 * 2048;
    __bf16* wkb = w; w += (size_t)512 * 2048;
    __bf16* wvb = w; w += (size_t)512 * 2048;
    __bf16* wob = w; w += (size_t)2048 * 2048;
    __bf16* qp  = w; w += (size_t)4096 * 2048;
    __bf16* kp  = w; w += (size_t)4096 * 512;
    __bf16* vpT = w; w += (size_t)512 * 4096;
    __bf16* ao  = w; w += (size_t)4096 * 2048;

    F2BArgs fa;
    fa.src[0] = query; fa.dst[0] = qb;
    fa.src[1] = key;   fa.dst[1] = kb;
    fa.src[2] = value; fa.dst[2] = vb;
    fa.src[3] = WQ;    fa.dst[3] = wqb;
    fa.src[4] = WK;    fa.dst[4] = wkb;
    fa.src[5] = WV;    fa.dst[5] = wvb;
    fa.src[6] = WO;    fa.dst[6] = wob;
    const long n8s[7] = {1048576, 1048576, 1048576, 524288, 131072, 131072, 524288};
    long acc = 0;
    for (int i = 0; i < 7; ++i) { fa.beg[i] = acc; acc += n8s[i]; }
    fa.beg[7] = acc;
    f2b_multi<<<2048, 256, 0, stream>>>(fa);

    gemm256<0><<<256, 512, 0, stream>>>(qb, wqb, bQ, nullptr, qp, 4096, 2048, 2048, 16);
    gemm_kv<<<256, 256, 0, stream>>>(kb, wkb, bK, kp, wvb, vb, bV, vpT);

    attn_kernel<<<512, 512, 0, stream>>>(qp, kp, vpT, ao);

    gemm256<1><<<256, 512, 0, stream>>>(ao, wob, bO, out, nullptr, 4096, 2048, 2048, 16);
}

// Round 11
// 252.421 us; speedup vs baseline: 1.3654x; 1.3654x over previous
//
#include <hip/hip_runtime.h>
#include <cstdint>
#include <cstddef>

// ---------------------------------------------------------------------------
// Fused GQA MHA: B=2 S=2048 D=2048, G=4 HPG=4 DH=128 (16 heads)
// fused fp32->bf16 | gemm_proj (Q,K,V^T in one dispatch) | flash attn | O proj
// ---------------------------------------------------------------------------

typedef __attribute__((ext_vector_type(8)))  __bf16 bf16x8;
typedef __attribute__((ext_vector_type(4)))  __bf16 bf16x4;
typedef __attribute__((ext_vector_type(4)))  float  f32x4;
typedef __attribute__((ext_vector_type(16))) float  f32x16;
typedef __attribute__((ext_vector_type(4)))  unsigned int u32x4;

#define GLD16(gp, lp) __builtin_amdgcn_global_load_lds(                         \
    (__attribute__((address_space(1))) void*)(size_t)(gp),                     \
    (__attribute__((address_space(3))) void*)(lp), 16, 0, 0)

#define PLSWAP(a, b) asm volatile("v_permlane32_swap_b32 %0, %1" : "+v"(a), "+v"(b))
#define EXP2F(x) __builtin_amdgcn_exp2f(x)

static __device__ __forceinline__ unsigned pack2bf(float a, float b) {
    unsigned short ua = __builtin_bit_cast(unsigned short, (__bf16)a);
    unsigned short ub = __builtin_bit_cast(unsigned short, (__bf16)b);
    return (unsigned)ua | ((unsigned)ub << 16);
}

// ---------------------------------------------------------------------------
// Fused fp32->bf16 for all 7 tensors in one launch
// ---------------------------------------------------------------------------
struct F2BArgs {
    const float* src[7];
    __bf16* dst[7];
    long beg[8];
};
__global__ void f2b_multi(F2BArgs a) {
    const long total = a.beg[7];
    const long stride = (long)gridDim.x * blockDim.x;
    for (long i = (long)blockIdx.x * blockDim.x + threadIdx.x; i < total; i += stride) {
        int s = 0;
#pragma unroll
        for (int j = 1; j < 7; ++j) s += (i >= a.beg[j]);
        long off = i - a.beg[s];
        const float4* p = (const float4*)(a.src[s] + off * 8);
        float4 x = p[0], y = p[1];
        bf16x8 r;
        r[0] = (__bf16)x.x; r[1] = (__bf16)x.y; r[2] = (__bf16)x.z; r[3] = (__bf16)x.w;
        r[4] = (__bf16)y.x; r[5] = (__bf16)y.y; r[6] = (__bf16)y.z; r[7] = (__bf16)y.w;
        *(bf16x8*)(a.dst[s] + off * 8) = r;
    }
}

// ---------------------------------------------------------------------------
// gemm256 body: C[*,N] tile (256x128) = A[*,K]*B[N,K]^T + bias. BK=64, 8 waves,
// triple-buffered LDS, 2 phases/K-tile, counted vmcnt(6). (R6-verified)
// ---------------------------------------------------------------------------
template <int OUTF32>
static __device__ __forceinline__
void gemm256_body(const __bf16* __restrict__ A, const __bf16* __restrict__ Bm,
                  const float* __restrict__ bias, float* __restrict__ Cf,
                  __bf16* __restrict__ Cb, int N, int K, int m0, int n0,
                  int biasrow, __bf16* As, __bf16* Bs) {
    const int tid = threadIdx.x, lane = tid & 63, wid = tid >> 6;
    const int g = lane >> 4, c = lane & 15;
    const int wr = wid >> 1, wc = wid & 1;
    const int nkt = K >> 6;

    const f32x4 z = {0.f, 0.f, 0.f, 0.f};
    f32x4 acc[4][4];
#pragma unroll
    for (int i = 0; i < 4; ++i)
#pragma unroll
        for (int j = 0; j < 4; ++j) acc[i][j] = z;

    auto stageA = [&](int b, int kt, int h) {
        if (kt >= nkt) return;
        const __bf16* src = A + (size_t)m0 * K + (size_t)kt * 64;
#pragma unroll
        for (int i = 0; i < 2; ++i) {
            int ci = h * 1024 + i * 512 + tid;
            int row = ci >> 3, chg = (ci & 7) ^ (row & 7);
            GLD16(src + (size_t)row * K + chg * 8, &As[b * 16384 + ci * 8]);
        }
    };
    auto stageB = [&](int b, int kt) {
        if (kt >= nkt) return;
        const __bf16* src = Bm + (size_t)n0 * K + (size_t)kt * 64;
#pragma unroll
        for (int i = 0; i < 2; ++i) {
            int ci = i * 512 + tid;
            int row = ci >> 3, chg = (ci & 7) ^ (row & 7);
            GLD16(src + (size_t)row * K + chg * 8, &Bs[b * 8192 + ci * 8]);
        }
    };

    stageA(0, 0, 0); stageA(0, 0, 1); stageB(0, 0);
    stageA(1, 1, 0); stageA(1, 1, 1); stageB(1, 1);
    asm volatile("s_waitcnt vmcnt(6)" ::: "memory");
    __builtin_amdgcn_sched_barrier(0);
    __builtin_amdgcn_s_barrier();

    int bd = 0;
    for (int kt = 0; kt < nkt; ++kt) {
        const int bs = (bd >= 1) ? bd - 1 : 2;
        bf16x8 af[4], bfr[4];
#pragma unroll
        for (int ph = 0; ph < 2; ++ph) {
#pragma unroll
            for (int mi = 0; mi < 4; ++mi) {
                int row = wr * 64 + mi * 16 + c;
                int ch = (ph * 4 + g) ^ (c & 7);
                af[mi] = *(const bf16x8*)&As[bd * 16384 + row * 64 + ch * 8];
            }
#pragma unroll
            for (int ni = 0; ni < 4; ++ni) {
                int row = wc * 64 + ni * 16 + c;
                int ch = (ph * 4 + g) ^ (c & 7);
                bfr[ni] = *(const bf16x8*)&Bs[bd * 8192 + row * 64 + ch * 8];
            }
            if (ph == 0) {
                stageA(bs, kt + 2, 0);
            } else {
                stageA(bs, kt + 2, 1);
                stageB(bs, kt + 2);
            }
            __builtin_amdgcn_s_barrier();
            asm volatile("s_waitcnt lgkmcnt(0)" ::: "memory");
            __builtin_amdgcn_sched_barrier(0);
            __builtin_amdgcn_s_setprio(1);
#pragma unroll
            for (int mi = 0; mi < 4; ++mi)
#pragma unroll
                for (int ni = 0; ni < 4; ++ni)
                    acc[mi][ni] = __builtin_amdgcn_mfma_f32_16x16x32_bf16(
                        af[mi], bfr[ni], acc[mi][ni], 0, 0, 0);
            __builtin_amdgcn_s_setprio(0);
            if (ph == 1) {
                if (kt >= nkt - 2) asm volatile("s_waitcnt vmcnt(0)" ::: "memory");
                else               asm volatile("s_waitcnt vmcnt(6)" ::: "memory");
                __builtin_amdgcn_sched_barrier(0);
            }
            __builtin_amdgcn_s_barrier();
        }
        bd = (bd >= 2) ? 0 : bd + 1;
    }

#pragma unroll
    for (int mi = 0; mi < 4; ++mi) {
#pragma unroll
        for (int ni = 0; ni < 4; ++ni) {
            int col = n0 + wc * 64 + ni * 16 + c;
            float bvc = biasrow ? 0.f : bias[col];
#pragma unroll
            for (int r = 0; r < 4; ++r) {
                int row = m0 + wr * 64 + mi * 16 + g * 4 + r;
                float v = acc[mi][ni][r] + (biasrow ? bias[row] : bvc);
                if (OUTF32) Cf[(size_t)row * N + col] = v;
                else        Cb[(size_t)row * N + col] = (__bf16)v;
            }
        }
    }
}

// All projections in one dispatch: blocks [0,256)=Q, [256,320)=K, [320,384)=V^T
__global__ __launch_bounds__(512)
void gemm_proj(const __bf16* __restrict__ qb, const __bf16* __restrict__ wqb,
               const float* __restrict__ bQ, __bf16* __restrict__ qp,
               const __bf16* __restrict__ kb, const __bf16* __restrict__ wkb,
               const float* __restrict__ bK, __bf16* __restrict__ kp,
               const __bf16* __restrict__ wvb, const __bf16* __restrict__ vb,
               const float* __restrict__ bV, __bf16* __restrict__ vpT) {
    __shared__ __bf16 As[3 * 256 * 64];
    __shared__ __bf16 Bs[3 * 128 * 64];
    const int bid = blockIdx.x;
    const int swz = (bid & 7) * 48 + (bid >> 3);   // 384 = 48*8, bijective
    if (swz < 256) {
        int bx = swz & 15, by = swz >> 4;
        gemm256_body<0>(qb, wqb, bQ, nullptr, qp, 2048, 2048,
                        by * 256, bx * 128, 0, As, Bs);
    } else if (swz < 320) {
        int s = swz - 256;
        int bx = s & 3, by = s >> 2;               // 4 x 16
        gemm256_body<0>(kb, wkb, bK, nullptr, kp, 512, 2048,
                        by * 256, bx * 128, 0, As, Bs);
    } else {
        int s = swz - 320;
        int bx = s & 31, by = s >> 5;              // 32 x 2
        gemm256_body<0>(wvb, vb, bV, nullptr, vpT, 4096, 2048,
                        by * 256, bx * 128, 1, As, Bs);
    }
}

// O projection (fp32 out), 256 blocks
__global__ __launch_bounds__(512)
void gemm_out(const __bf16* __restrict__ A, const __bf16* __restrict__ Bm,
              const float* __restrict__ bias, float* __restrict__ Cf) {
    __shared__ __bf16 As[3 * 256 * 64];
    __shared__ __bf16 Bs[3 * 128 * 64];
    const int bid = blockIdx.x;
    const int swz = (bid & 7) * 32 + (bid >> 3);
    int bx = swz & 15, by = swz >> 4;
    gemm256_body<1>(A, Bm, bias, Cf, nullptr, 2048, 2048,
                    by * 256, bx * 128, 0, As, Bs);
}

// ---------------------------------------------------------------------------
// Flash attention (verbatim R9 — verified 119 us): 32x32x16 swapped-operand,
// XCD-exact placement, staggered start, KVBLK=32, triple-buffered K/V^T,
// pipeline depth 2, counted vmcnt(4) + raw s_barrier.
// ---------------------------------------------------------------------------
__global__ __launch_bounds__(256)
void attn_kernel(const __bf16* __restrict__ Qw, const __bf16* __restrict__ Kw,
                 const __bf16* __restrict__ VTw, __bf16* __restrict__ Ow) {
    constexpr int S = 2048, DQ = 2048, DKV = 512, TOK = 4096;
    constexpr int nt = S / 32;
    const int bid = blockIdx.x;
    const int xcd = bid & 7, slot = bid >> 3;
    const int b = xcd >> 2, grp = xcd & 3;
    const int head = grp * 4 + (slot & 3);
    const int qblk = slot >> 2;
    const int t0 = slot & (nt - 1);
    const __bf16* Q   = Qw + (size_t)b * S * DQ + head * 128;
    const __bf16* Kp  = Kw + (size_t)b * S * DKV + grp * 128;
    const __bf16* VTp = VTw + (size_t)(grp * 128) * TOK + (size_t)b * S;
    __bf16* Op = Ow + (size_t)b * S * DQ + head * 128;

    __shared__ __bf16 Ks[3][32 * 128];
    __shared__ __bf16 Vs[3][128 * 32];

    const int tid = threadIdx.x, wid = tid >> 6, lane = tid & 63;
    const int ql = lane & 31, hi = lane >> 5;
    const int qrow = qblk * 128 + wid * 32 + ql;

    bf16x8 qf[8];
#pragma unroll
    for (int ks = 0; ks < 8; ++ks)
        qf[ks] = *(const bf16x8*)(Q + (size_t)qrow * DQ + ks * 16 + hi * 8);

    f32x16 o[4];
#pragma unroll
    for (int d = 0; d < 4; ++d)
#pragma unroll
        for (int r = 0; r < 16; ++r) o[d][r] = 0.f;
    float mprev = -1e30f, lsum = 0.f;
    constexpr float kexp = 0.08838834764831845f * 1.4426950408889634f;
    constexpr float THR = 8.0f / kexp;

    auto stage = [&](int buf, int t) {
#pragma unroll
        for (int i = 0; i < 2; ++i) {
            int ci = i * 256 + tid;
            int key = ci >> 4, ccl = ci & 15, ccg = ccl ^ (key & 15);
            GLD16(Kp + (size_t)(t * 32 + key) * DKV + ccg * 8, &Ks[buf][ci * 8]);
        }
#pragma unroll
        for (int i = 0; i < 2; ++i) {
            int ci = i * 256 + tid;
            int dh = ci >> 2, cl = ci & 3, cg = cl ^ ((dh >> 1) & 3);
            GLD16(VTp + (size_t)dh * TOK + t * 32 + cg * 8, &Vs[buf][ci * 8]);
        }
    };

    stage(0, t0);
    stage(1, (t0 + 1) & (nt - 1));
    asm volatile("s_waitcnt vmcnt(4)" ::: "memory");
    asm volatile("s_barrier" ::: "memory");

    int bc = 0;
    for (int i = 0; i < nt; ++i) {
        const int bs = (bc >= 1) ? bc - 1 : 2;
        if (i + 2 < nt) stage(bs, (t0 + i + 2) & (nt - 1));

        f32x16 sc;
#pragma unroll
        for (int r = 0; r < 16; ++r) sc[r] = 0.f;
        __builtin_amdgcn_s_setprio(1);
#pragma unroll
        for (int ks = 0; ks < 8; ++ks) {
            int chl = (ks * 2 + hi) ^ (ql & 15);
            bf16x8 kf = *(const bf16x8*)&Ks[bc][ql * 128 + chl * 8];
            sc = __builtin_amdgcn_mfma_f32_32x32x16_bf16(kf, qf[ks], sc, 0, 0, 0);
        }
        __builtin_amdgcn_s_setprio(0);

        float mo = sc[0];
#pragma unroll
        for (int r = 1; r < 16; ++r) mo = fmaxf(mo, sc[r]);
        mo = fmaxf(mo, __shfl_xor(mo, 32, 64));
        if (!__all(mo - mprev <= THR)) {
            float mn = fmaxf(mprev, mo);
            float ef = EXP2F((mprev - mn) * kexp);
            lsum *= ef;
#pragma unroll
            for (int d = 0; d < 4; ++d)
#pragma unroll
                for (int r = 0; r < 16; ++r) o[d][r] *= ef;
            mprev = mn;
        }
        float mnk = mprev * kexp;
        float rs = 0.f;
#pragma unroll
        for (int r = 0; r < 16; ++r) {
            float p = EXP2F(__builtin_fmaf(sc[r], kexp, -mnk));
            sc[r] = p;
            rs += p;
        }
        rs += __shfl_xor(rs, 32, 64);
        lsum += rs;

        unsigned pk[4][2];
#pragma unroll
        for (int rg = 0; rg < 4; ++rg) {
            pk[rg][0] = pack2bf(sc[rg * 4 + 0], sc[rg * 4 + 1]);
            pk[rg][1] = pack2bf(sc[rg * 4 + 2], sc[rg * 4 + 3]);
        }

        __builtin_amdgcn_s_setprio(1);
#pragma unroll
        for (int e = 0; e < 2; ++e) {
            unsigned a0 = pk[2 * e][0], b0 = pk[2 * e + 1][0];
            unsigned a1 = pk[2 * e][1], b1 = pk[2 * e + 1][1];
            PLSWAP(a0, b0);
            PLSWAP(a1, b1);
            u32x4 fw = {a0, a1, b0, b1};
            bf16x8 pf = __builtin_bit_cast(bf16x8, fw);
#pragma unroll
            for (int dht = 0; dht < 4; ++dht) {
                int dh = dht * 32 + ql;
                int chl = (e * 2 + hi) ^ ((dh >> 1) & 3);
                bf16x8 vf = *(const bf16x8*)&Vs[bc][dh * 32 + chl * 8];
                o[dht] = __builtin_amdgcn_mfma_f32_32x32x16_bf16(vf, pf, o[dht], 0, 0, 0);
            }
        }
        __builtin_amdgcn_s_setprio(0);

        if (i + 2 < nt) asm volatile("s_waitcnt vmcnt(4)" ::: "memory");
        else            asm volatile("s_waitcnt vmcnt(0)" ::: "memory");
        asm volatile("s_barrier" ::: "memory");
        bc = (bc >= 2) ? 0 : bc + 1;
    }

    float inv = 1.0f / lsum;
#pragma unroll
    for (int dht = 0; dht < 4; ++dht)
#pragma unroll
        for (int rg = 0; rg < 4; ++rg) {
            bf16x4 wv;
#pragma unroll
            for (int j = 0; j < 4; ++j) wv[j] = (__bf16)(o[dht][rg * 4 + j] * inv);
            int dh0 = dht * 32 + rg * 8 + hi * 4;
            *(bf16x4*)(Op + (size_t)qrow * DQ + dh0) = wv;
        }
}

// ---------------------------------------------------------------------------
extern "C" void kernel_launch(void* const* d_in, const int* in_sizes, int n_in,
                              void* d_out, int out_size, void* d_ws, size_t ws_size,
                              hipStream_t stream) {
    (void)in_sizes; (void)n_in; (void)out_size; (void)ws_size;
    const float* query = (const float*)d_in[0];
    const float* key   = (const float*)d_in[1];
    const float* value = (const float*)d_in[2];
    const float* WQ = (const float*)d_in[3];
    const float* bQ = (const float*)d_in[4];
    const float* WK = (const float*)d_in[5];
    const float* bK = (const float*)d_in[6];
    const float* WV = (const float*)d_in[7];
    const float* bV = (const float*)d_in[8];
    const float* WO = (const float*)d_in[9];
    const float* bO = (const float*)d_in[10];
    float* out = (float*)d_out;

    __bf16* w = (__bf16*)d_ws;
    __bf16* qb  = w; w += (size_t)4096 * 2048;
    __bf16* kb  = w; w += (size_t)4096 * 2048;
    __bf16* vb  = w; w += (size_t)4096 * 2048;
    __bf16* wqb = w; w += (size_t)2048 * 2048;
    __bf16* wkb = w; w += (size_t)512 * 2048;
    __bf16* wvb = w; w += (size_t)512 * 2048;
    __bf16* wob = w; w += (size_t)2048 * 2048;
    __bf16* qp  = w; w += (size_t)4096 * 2048;
    __bf16* kp  = w; w += (size_t)4096 * 512;
    __bf16* vpT = w; w += (size_t)512 * 4096;
    __bf16* ao  = w; w += (size_t)4096 * 2048;

    F2BArgs fa;
    fa.src[0] = query; fa.dst[0] = qb;
    fa.src[1] = key;   fa.dst[1] = kb;
    fa.src[2] = value; fa.dst[2] = vb;
    fa.src[3] = WQ;    fa.dst[3] = wqb;
    fa.src[4] = WK;    fa.dst[4] = wkb;
    fa.src[5] = WV;    fa.dst[5] = wvb;
    fa.src[6] = WO;    fa.dst[6] = wob;
    const long n8s[7] = {1048576, 1048576, 1048576, 524288, 131072, 131072, 524288};
    long acc = 0;
    for (int i = 0; i < 7; ++i) { fa.beg[i] = acc; acc += n8s[i]; }
    fa.beg[7] = acc;
    f2b_multi<<<2048, 256, 0, stream>>>(fa);

    // all projections (Q + K + V^T), one dispatch, 384 blocks
    gemm_proj<<<384, 512, 0, stream>>>(qb, wqb, bQ, qp,
                                       kb, wkb, bK, kp,
                                       wvb, vb, bV, vpT);

    attn_kernel<<<512, 256, 0, stream>>>(qp, kp, vpT, ao);

    gemm_out<<<256, 512, 0, stream>>>(ao, wob, bO, out);
}

// Round 12
// 246.527 us; speedup vs baseline: 1.3981x; 1.0239x over previous
//
#include <hip/hip_runtime.h>
#include <cstdint>
#include <cstddef>

// ---------------------------------------------------------------------------
// Fused GQA MHA: B=2 S=2048 D=2048, G=4 HPG=4 DH=128 (16 heads)
// fused fp32->bf16 | gemm_proj (Q,K,V^T one dispatch) | flash attn | O proj
// ---------------------------------------------------------------------------

typedef __attribute__((ext_vector_type(8)))  __bf16 bf16x8;
typedef __attribute__((ext_vector_type(4)))  __bf16 bf16x4;
typedef __attribute__((ext_vector_type(4)))  float  f32x4;
typedef __attribute__((ext_vector_type(16))) float  f32x16;
typedef __attribute__((ext_vector_type(4)))  unsigned int u32x4;

#define GLD16(gp, lp) __builtin_amdgcn_global_load_lds(                         \
    (__attribute__((address_space(1))) void*)(size_t)(gp),                     \
    (__attribute__((address_space(3))) void*)(lp), 16, 0, 0)

#define PLSWAP(a, b) asm volatile("v_permlane32_swap_b32 %0, %1" : "+v"(a), "+v"(b))
#define EXP2F(x) __builtin_amdgcn_exp2f(x)

static __device__ __forceinline__ unsigned pack2bf(float a, float b) {
    unsigned short ua = __builtin_bit_cast(unsigned short, (__bf16)a);
    unsigned short ub = __builtin_bit_cast(unsigned short, (__bf16)b);
    return (unsigned)ua | ((unsigned)ub << 16);
}

// ---------------------------------------------------------------------------
// Fused fp32->bf16 for all 7 tensors in one launch
// ---------------------------------------------------------------------------
struct F2BArgs {
    const float* src[7];
    __bf16* dst[7];
    long beg[8];
};
__global__ void f2b_multi(F2BArgs a) {
    const long total = a.beg[7];
    const long stride = (long)gridDim.x * blockDim.x;
    for (long i = (long)blockIdx.x * blockDim.x + threadIdx.x; i < total; i += stride) {
        int s = 0;
#pragma unroll
        for (int j = 1; j < 7; ++j) s += (i >= a.beg[j]);
        long off = i - a.beg[s];
        const float4* p = (const float4*)(a.src[s] + off * 8);
        float4 x = p[0], y = p[1];
        bf16x8 r;
        r[0] = (__bf16)x.x; r[1] = (__bf16)x.y; r[2] = (__bf16)x.z; r[3] = (__bf16)x.w;
        r[4] = (__bf16)y.x; r[5] = (__bf16)y.y; r[6] = (__bf16)y.z; r[7] = (__bf16)y.w;
        *(bf16x8*)(a.dst[s] + off * 8) = r;
    }
}

// ---------------------------------------------------------------------------
// gemm256 body (R6-verified): 256x128 tile, BK=64, 8 waves, triple-buffered,
// counted vmcnt(6)
// ---------------------------------------------------------------------------
template <int OUTF32>
static __device__ __forceinline__
void gemm256_body(const __bf16* __restrict__ A, const __bf16* __restrict__ Bm,
                  const float* __restrict__ bias, float* __restrict__ Cf,
                  __bf16* __restrict__ Cb, int N, int K, int m0, int n0,
                  int biasrow, __bf16* As, __bf16* Bs) {
    const int tid = threadIdx.x, lane = tid & 63, wid = tid >> 6;
    const int g = lane >> 4, c = lane & 15;
    const int wr = wid >> 1, wc = wid & 1;
    const int nkt = K >> 6;

    const f32x4 z = {0.f, 0.f, 0.f, 0.f};
    f32x4 acc[4][4];
#pragma unroll
    for (int i = 0; i < 4; ++i)
#pragma unroll
        for (int j = 0; j < 4; ++j) acc[i][j] = z;

    auto stageA = [&](int b, int kt, int h) {
        if (kt >= nkt) return;
        const __bf16* src = A + (size_t)m0 * K + (size_t)kt * 64;
#pragma unroll
        for (int i = 0; i < 2; ++i) {
            int ci = h * 1024 + i * 512 + tid;
            int row = ci >> 3, chg = (ci & 7) ^ (row & 7);
            GLD16(src + (size_t)row * K + chg * 8, &As[b * 16384 + ci * 8]);
        }
    };
    auto stageB = [&](int b, int kt) {
        if (kt >= nkt) return;
        const __bf16* src = Bm + (size_t)n0 * K + (size_t)kt * 64;
#pragma unroll
        for (int i = 0; i < 2; ++i) {
            int ci = i * 512 + tid;
            int row = ci >> 3, chg = (ci & 7) ^ (row & 7);
            GLD16(src + (size_t)row * K + chg * 8, &Bs[b * 8192 + ci * 8]);
        }
    };

    stageA(0, 0, 0); stageA(0, 0, 1); stageB(0, 0);
    stageA(1, 1, 0); stageA(1, 1, 1); stageB(1, 1);
    asm volatile("s_waitcnt vmcnt(6)" ::: "memory");
    __builtin_amdgcn_sched_barrier(0);
    __builtin_amdgcn_s_barrier();

    int bd = 0;
    for (int kt = 0; kt < nkt; ++kt) {
        const int bs = (bd >= 1) ? bd - 1 : 2;
        bf16x8 af[4], bfr[4];
#pragma unroll
        for (int ph = 0; ph < 2; ++ph) {
#pragma unroll
            for (int mi = 0; mi < 4; ++mi) {
                int row = wr * 64 + mi * 16 + c;
                int ch = (ph * 4 + g) ^ (c & 7);
                af[mi] = *(const bf16x8*)&As[bd * 16384 + row * 64 + ch * 8];
            }
#pragma unroll
            for (int ni = 0; ni < 4; ++ni) {
                int row = wc * 64 + ni * 16 + c;
                int ch = (ph * 4 + g) ^ (c & 7);
                bfr[ni] = *(const bf16x8*)&Bs[bd * 8192 + row * 64 + ch * 8];
            }
            if (ph == 0) {
                stageA(bs, kt + 2, 0);
            } else {
                stageA(bs, kt + 2, 1);
                stageB(bs, kt + 2);
            }
            __builtin_amdgcn_s_barrier();
            asm volatile("s_waitcnt lgkmcnt(0)" ::: "memory");
            __builtin_amdgcn_sched_barrier(0);
            __builtin_amdgcn_s_setprio(1);
#pragma unroll
            for (int mi = 0; mi < 4; ++mi)
#pragma unroll
                for (int ni = 0; ni < 4; ++ni)
                    acc[mi][ni] = __builtin_amdgcn_mfma_f32_16x16x32_bf16(
                        af[mi], bfr[ni], acc[mi][ni], 0, 0, 0);
            __builtin_amdgcn_s_setprio(0);
            if (ph == 1) {
                if (kt >= nkt - 2) asm volatile("s_waitcnt vmcnt(0)" ::: "memory");
                else               asm volatile("s_waitcnt vmcnt(6)" ::: "memory");
                __builtin_amdgcn_sched_barrier(0);
            }
            __builtin_amdgcn_s_barrier();
        }
        bd = (bd >= 2) ? 0 : bd + 1;
    }

#pragma unroll
    for (int mi = 0; mi < 4; ++mi) {
#pragma unroll
        for (int ni = 0; ni < 4; ++ni) {
            int col = n0 + wc * 64 + ni * 16 + c;
            float bvc = biasrow ? 0.f : bias[col];
#pragma unroll
            for (int r = 0; r < 4; ++r) {
                int row = m0 + wr * 64 + mi * 16 + g * 4 + r;
                float v = acc[mi][ni][r] + (biasrow ? bias[row] : bvc);
                if (OUTF32) Cf[(size_t)row * N + col] = v;
                else        Cb[(size_t)row * N + col] = (__bf16)v;
            }
        }
    }
}

// All projections in one dispatch: blocks [0,256)=Q, [256,320)=K, [320,384)=V^T
__global__ __launch_bounds__(512)
void gemm_proj(const __bf16* __restrict__ qb, const __bf16* __restrict__ wqb,
               const float* __restrict__ bQ, __bf16* __restrict__ qp,
               const __bf16* __restrict__ kb, const __bf16* __restrict__ wkb,
               const float* __restrict__ bK, __bf16* __restrict__ kp,
               const __bf16* __restrict__ wvb, const __bf16* __restrict__ vb,
               const float* __restrict__ bV, __bf16* __restrict__ vpT) {
    __shared__ __bf16 As[3 * 256 * 64];
    __shared__ __bf16 Bs[3 * 128 * 64];
    const int bid = blockIdx.x;
    const int swz = (bid & 7) * 48 + (bid >> 3);   // 384 = 48*8, bijective
    if (swz < 256) {
        int bx = swz & 15, by = swz >> 4;
        gemm256_body<0>(qb, wqb, bQ, nullptr, qp, 2048, 2048,
                        by * 256, bx * 128, 0, As, Bs);
    } else if (swz < 320) {
        int s = swz - 256;
        int bx = s & 3, by = s >> 2;
        gemm256_body<0>(kb, wkb, bK, nullptr, kp, 512, 2048,
                        by * 256, bx * 128, 0, As, Bs);
    } else {
        int s = swz - 320;
        int bx = s & 31, by = s >> 5;
        gemm256_body<0>(wvb, vb, bV, nullptr, vpT, 4096, 2048,
                        by * 256, bx * 128, 1, As, Bs);
    }
}

// O projection (fp32 out), 256 blocks
__global__ __launch_bounds__(512)
void gemm_out(const __bf16* __restrict__ A, const __bf16* __restrict__ Bm,
              const float* __restrict__ bias, float* __restrict__ Cf) {
    __shared__ __bf16 As[3 * 256 * 64];
    __shared__ __bf16 Bs[3 * 128 * 64];
    const int bid = blockIdx.x;
    const int swz = (bid & 7) * 32 + (bid >> 3);
    int bx = swz & 15, by = swz >> 4;
    gemm256_body<1>(A, Bm, bias, Cf, nullptr, 2048, 2048,
                    by * 256, bx * 128, 0, As, Bs);
}

// ---------------------------------------------------------------------------
// Flash attention: R9 base (KVBLK=32, triple-buffered, counted vmcnt) + T15
// att[2] double-pipeline: iter i = { stage(i+2) | QK^T(i+1)->scB (MFMA pipe)
// | softmax+pack(scA) (VALU, overlaps) | PV(i) } with vmcnt(2) per iter
// (retires V(i+1)+K(i+2); leaves V(i+2) in flight).
// ---------------------------------------------------------------------------
__global__ __launch_bounds__(256)
void attn_kernel(const __bf16* __restrict__ Qw, const __bf16* __restrict__ Kw,
                 const __bf16* __restrict__ VTw, __bf16* __restrict__ Ow) {
    constexpr int S = 2048, DQ = 2048, DKV = 512, TOK = 4096;
    constexpr int nt = S / 32;                    // 64 tiles of 32 keys
    const int bid = blockIdx.x;
    const int xcd = bid & 7, slot = bid >> 3;
    const int b = xcd >> 2, grp = xcd & 3;
    const int head = grp * 4 + (slot & 3);
    const int qblk = slot >> 2;
    const int t0 = slot & (nt - 1);
    const __bf16* Q   = Qw + (size_t)b * S * DQ + head * 128;
    const __bf16* Kp  = Kw + (size_t)b * S * DKV + grp * 128;
    const __bf16* VTp = VTw + (size_t)(grp * 128) * TOK + (size_t)b * S;
    __bf16* Op = Ow + (size_t)b * S * DQ + head * 128;

    __shared__ __bf16 Ks[3][32 * 128];   // 24 KB
    __shared__ __bf16 Vs[3][128 * 32];   // 24 KB

    const int tid = threadIdx.x, wid = tid >> 6, lane = tid & 63;
    const int ql = lane & 31, hi = lane >> 5;
    const int qrow = qblk * 128 + wid * 32 + ql;

    bf16x8 qf[8];
#pragma unroll
    for (int ks = 0; ks < 8; ++ks)
        qf[ks] = *(const bf16x8*)(Q + (size_t)qrow * DQ + ks * 16 + hi * 8);

    f32x16 o[4];
#pragma unroll
    for (int d = 0; d < 4; ++d)
#pragma unroll
        for (int r = 0; r < 16; ++r) o[d][r] = 0.f;
    float mprev = -1e30f, lsum = 0.f;
    constexpr float kexp = 0.08838834764831845f * 1.4426950408889634f;
    constexpr float THR = 8.0f / kexp;

    // stage logical tile t into buffer t%3 (K first, then V — vmcnt order)
    auto stage = [&](int t) {
        int buf = t % 3;
        int ta = (t0 + t) & (nt - 1);
#pragma unroll
        for (int i = 0; i < 2; ++i) {
            int ci = i * 256 + tid;
            int key = ci >> 4, ccl = ci & 15, ccg = ccl ^ (key & 15);
            GLD16(Kp + (size_t)(ta * 32 + key) * DKV + ccg * 8, &Ks[buf][ci * 8]);
        }
#pragma unroll
        for (int i = 0; i < 2; ++i) {
            int ci = i * 256 + tid;
            int dh = ci >> 2, cl = ci & 3, cg = cl ^ ((dh >> 1) & 3);
            GLD16(VTp + (size_t)dh * TOK + ta * 32 + cg * 8, &Vs[buf][ci * 8]);
        }
    };

    // QK^T of logical tile t into scn (16 MFMA, independent of scA/scB swap)
    auto qkt = [&](int t, f32x16& scn) {
        const __bf16* kb = &Ks[t % 3][0];
#pragma unroll
        for (int r = 0; r < 16; ++r) scn[r] = 0.f;
        __builtin_amdgcn_s_setprio(1);
#pragma unroll
        for (int ks = 0; ks < 8; ++ks) {
            int chl = (ks * 2 + hi) ^ (ql & 15);
            bf16x8 kf = *(const bf16x8*)&kb[ql * 128 + chl * 8];
            scn = __builtin_amdgcn_mfma_f32_32x32x16_bf16(kf, qf[ks], scn, 0, 0, 0);
        }
        __builtin_amdgcn_s_setprio(0);
    };

    // softmax + pack + PV of logical tile t using sc
    auto smpv = [&](int t, f32x16& sc) {
        const __bf16* vb = &Vs[t % 3][0];
        float mo = sc[0];
#pragma unroll
        for (int r = 1; r < 16; ++r) mo = fmaxf(mo, sc[r]);
        mo = fmaxf(mo, __shfl_xor(mo, 32, 64));
        if (!__all(mo - mprev <= THR)) {          // T13 defer-max
            float mn = fmaxf(mprev, mo);
            float ef = EXP2F((mprev - mn) * kexp);
            lsum *= ef;
#pragma unroll
            for (int d = 0; d < 4; ++d)
#pragma unroll
                for (int r = 0; r < 16; ++r) o[d][r] *= ef;
            mprev = mn;
        }
        float mnk = mprev * kexp;
        float rs = 0.f;
#pragma unroll
        for (int r = 0; r < 16; ++r) {
            float p = EXP2F(__builtin_fmaf(sc[r], kexp, -mnk));
            sc[r] = p;
            rs += p;
        }
        rs += __shfl_xor(rs, 32, 64);
        lsum += rs;

        unsigned pk[4][2];
#pragma unroll
        for (int rg = 0; rg < 4; ++rg) {
            pk[rg][0] = pack2bf(sc[rg * 4 + 0], sc[rg * 4 + 1]);
            pk[rg][1] = pack2bf(sc[rg * 4 + 2], sc[rg * 4 + 3]);
        }

        __builtin_amdgcn_s_setprio(1);
#pragma unroll
        for (int e = 0; e < 2; ++e) {
            unsigned a0 = pk[2 * e][0], b0 = pk[2 * e + 1][0];
            unsigned a1 = pk[2 * e][1], b1 = pk[2 * e + 1][1];
            PLSWAP(a0, b0);
            PLSWAP(a1, b1);
            u32x4 fw = {a0, a1, b0, b1};
            bf16x8 pf = __builtin_bit_cast(bf16x8, fw);
#pragma unroll
            for (int dht = 0; dht < 4; ++dht) {
                int dh = dht * 32 + ql;
                int chl = (e * 2 + hi) ^ ((dh >> 1) & 3);
                bf16x8 vf = *(const bf16x8*)&vb[dh * 32 + chl * 8];
                o[dht] = __builtin_amdgcn_mfma_f32_32x32x16_bf16(vf, pf, o[dht], 0, 0, 0);
            }
        }
        __builtin_amdgcn_s_setprio(0);
    };

    // prologue: tiles 0,1 in flight; retire K0,V0,K1 (V1 stays in flight);
    // compute QK^T(0) -> scA
    f32x16 scA, scB;
    stage(0);
    stage(1);
    asm volatile("s_waitcnt vmcnt(2)" ::: "memory");
    asm volatile("s_barrier" ::: "memory");
    qkt(0, scA);

    for (int i = 0; i < nt; i += 2) {
        // even body: tile i (smpv), tile i+1 (qkt -> scB)
        if (i + 2 < nt) stage(i + 2);
        qkt(i + 1, scB);               // i+1 <= nt-1 always (nt even)
        smpv(i, scA);
        if (i + 2 < nt) asm volatile("s_waitcnt vmcnt(2)" ::: "memory");
        else            asm volatile("s_waitcnt vmcnt(0)" ::: "memory");
        asm volatile("s_barrier" ::: "memory");

        // odd body: tile i+1 (smpv), tile i+2 (qkt -> scA)
        if (i + 3 < nt) stage(i + 3);
        if (i + 2 < nt) qkt(i + 2, scA);
        smpv(i + 1, scB);
        if (i + 3 < nt) asm volatile("s_waitcnt vmcnt(2)" ::: "memory");
        else            asm volatile("s_waitcnt vmcnt(0)" ::: "memory");
        asm volatile("s_barrier" ::: "memory");
    }

    // epilogue: dh = dht*32 + 8*(r>>2) + 4*hi + (r&3)
    float inv = 1.0f / lsum;
#pragma unroll
    for (int dht = 0; dht < 4; ++dht)
#pragma unroll
        for (int rg = 0; rg < 4; ++rg) {
            bf16x4 wv;
#pragma unroll
            for (int j = 0; j < 4; ++j) wv[j] = (__bf16)(o[dht][rg * 4 + j] * inv);
            int dh0 = dht * 32 + rg * 8 + hi * 4;
            *(bf16x4*)(Op + (size_t)qrow * DQ + dh0) = wv;
        }
}

// ---------------------------------------------------------------------------
extern "C" void kernel_launch(void* const* d_in, const int* in_sizes, int n_in,
                              void* d_out, int out_size, void* d_ws, size_t ws_size,
                              hipStream_t stream) {
    (void)in_sizes; (void)n_in; (void)out_size; (void)ws_size;
    const float* query = (const float*)d_in[0];
    const float* key   = (const float*)d_in[1];
    const float* value = (const float*)d_in[2];
    const float* WQ = (const float*)d_in[3];
    const float* bQ = (const float*)d_in[4];
    const float* WK = (const float*)d_in[5];
    const float* bK = (const float*)d_in[6];
    const float* WV = (const float*)d_in[7];
    const float* bV = (const float*)d_in[8];
    const float* WO = (const float*)d_in[9];
    const float* bO = (const float*)d_in[10];
    float* out = (float*)d_out;

    __bf16* w = (__bf16*)d_ws;
    __bf16* qb  = w; w += (size_t)4096 * 2048;
    __bf16* kb  = w; w += (size_t)4096 * 2048;
    __bf16* vb  = w; w += (size_t)4096 * 2048;
    __bf16* wqb = w; w += (size_t)2048 * 2048;
    __bf16* wkb = w; w += (size_t)512 * 2048;
    __bf16* wvb = w; w += (size_t)512 * 2048;
    __bf16* wob = w; w += (size_t)2048 * 2048;
    __bf16* qp  = w; w += (size_t)4096 * 2048;
    __bf16* kp  = w; w += (size_t)4096 * 512;
    __bf16* vpT = w; w += (size_t)512 * 4096;
    __bf16* ao  = w; w += (size_t)4096 * 2048;

    F2BArgs fa;
    fa.src[0] = query; fa.dst[0] = qb;
    fa.src[1] = key;   fa.dst[1] = kb;
    fa.src[2] = value; fa.dst[2] = vb;
    fa.src[3] = WQ;    fa.dst[3] = wqb;
    fa.src[4] = WK;    fa.dst[4] = wkb;
    fa.src[5] = WV;    fa.dst[5] = wvb;
    fa.src[6] = WO;    fa.dst[6] = wob;
    const long n8s[7] = {1048576, 1048576, 1048576, 524288, 131072, 131072, 524288};
    long acc = 0;
    for (int i = 0; i < 7; ++i) { fa.beg[i] = acc; acc += n8s[i]; }
    fa.beg[7] = acc;
    f2b_multi<<<2048, 256, 0, stream>>>(fa);

    gemm_proj<<<384, 512, 0, stream>>>(qb, wqb, bQ, qp,
                                       kb, wkb, bK, kp,
                                       wvb, vb, bV, vpT);

    attn_kernel<<<512, 256, 0, stream>>>(qp, kp, vpT, ao);

    gemm_out<<<256, 512, 0, stream>>>(ao, wob, bO, out);
}